// Round 4
// baseline (78.230 us; speedup 1.0000x reference)
//
#include <hip/hip_runtime.h>

#define NN 96
#define DD 64
#define HH 256
#define H2 128

// ---------------- Kernel A: projections (round-2 proven form) ----------------
__global__ __launch_bounds__(256) void proj_kernel(
    const float* __restrict__ X, const float* __restrict__ W1, const float* __restrict__ b1,
    const float* __restrict__ V1, const float* __restrict__ c1,
    float* __restrict__ pi, float* __restrict__ pj,
    float* __restrict__ ta, float* __restrict__ tb, float* __restrict__ tcT)
{
    const int i = blockIdx.x;
    const int h = threadIdx.x;          // 0..255
    __shared__ float xs[DD];
    if (h < DD) xs[h] = X[i*DD + h];
    __syncthreads();
    float aPi = 0.f, aPj = 0.f, aTa = 0.f, aTb = 0.f, aTc = 0.f;
    #pragma unroll 8
    for (int d = 0; d < DD; ++d) {
        const float x = xs[d];
        aPi = fmaf(x, W1[d*HH + h],          aPi);
        aPj = fmaf(x, W1[(DD + d)*HH + h],   aPj);
        aTa = fmaf(x, V1[d*HH + h],          aTa);
        aTb = fmaf(x, V1[(DD + d)*HH + h],   aTb);
        aTc = fmaf(x, V1[(2*DD + d)*HH + h], aTc);
    }
    pi[i*HH + h] = aPi + b1[h];
    pj[i*HH + h] = aPj;
    ta[i*HH + h] = aTa + c1[h];
    tb[i*HH + h] = aTb;
    tcT[h*NN + i] = aTc;
}

// ---------------- Kernel A2: S[i*96+j][h] = ta[i][h] + tb[j][h] ----------------
// 9.4 MB streamed write; removes conf's LDS staging + DS reads entirely.
__global__ __launch_bounds__(256) void sadd_kernel(
    const float* __restrict__ ta, const float* __restrict__ tb,
    float* __restrict__ S)
{
    const int idx = blockIdx.x*256 + threadIdx.x;   // 0..589823
    const int row = idx >> 6;                        // i*96 + j
    const int h4  = (idx & 63) << 2;
    const int i   = row / NN;                        // magic-div
    const int j   = row - i*NN;
    const float4 a = *(const float4*)&ta[i*HH + h4];
    const float4 b = *(const float4*)&tb[j*HH + h4];
    float4 s; s.x = a.x+b.x; s.y = a.y+b.y; s.z = a.z+b.z; s.w = a.w+b.w;
    *(float4*)&S[row*HH + h4] = s;
}

// ---------------- Kernel B: causal [96,96] ----------------
// grid (96,6): 16 j per block. 256 threads: qt = t>>6 (h-quarter per wave),
// jq = (t&63)>>4 (j-quad), cc = t&15 (c-lane; owns 8 channels cc+16u).
// One b128 hv broadcast now feeds 32 FMAs (was 12) -> DS pipe 11.5 -> 2.9 us.
// Stage writes XOR-quad swizzled (8-way instead of 32-way conflict);
// partials stored c-contiguous -> near-conflict-free epilogue.
__global__ __launch_bounds__(256) void causal_kernel(
    const float* __restrict__ pi, const float* __restrict__ pj,
    const float* __restrict__ W2, const float* __restrict__ b2,
    const float* __restrict__ W3, const float* __restrict__ b3,
    float* __restrict__ out)
{
    const int i  = blockIdx.x;
    const int j0 = blockIdx.y * 16;
    const int t  = threadIdx.x;         // 0..255
    const int qt   = t >> 6;            // 0..3 (wave id = h-quarter)
    const int lane = t & 63;
    const int jq   = lane >> 4;         // 0..3
    const int cc   = lane & 15;         // 0..15

    __shared__ float smem[32*16*16];    // 8192 floats = 32 KB (union)
    __shared__ float red[2][16];
    float (*hb)[16]       = (float(*)[16])smem;      // [256][16] (16 KB)
    float (*part)[16][16] = (float(*)[16][16])smem;  // [32][16][16] (32 KB)

    // ---- stage: data-quad d of row t stored at quad-position d^(t&3) ----
    {
        const float p_i = pi[i*HH + t];
        float v[16];
        #pragma unroll
        for (int jj = 0; jj < 16; ++jj)
            v[jj] = fmaxf(p_i + pj[(j0 + jj)*HH + t], 0.f);
        const int sx = t & 3;
        #pragma unroll
        for (int d = 0; d < 4; ++d) {
            float4 w; w.x = v[d*4]; w.y = v[d*4+1]; w.z = v[d*4+2]; w.w = v[d*4+3];
            *(float4*)&hb[t][((d ^ sx) << 2)] = w;
        }
    }
    __syncthreads();

    // ---- inner: 64 h per wave; acc[4 j][8 c] per lane ----
    float acc[4][8];
    #pragma unroll
    for (int jv = 0; jv < 4; ++jv)
        #pragma unroll
        for (int u = 0; u < 8; ++u) acc[jv][u] = 0.f;

    const float* __restrict__ w2p = W2 + cc;
    const int hbase = qt << 6;
    #pragma unroll 2
    for (int q = 0; q < 64; ++q) {
        const int hq = hbase + q;
        const float4 hv = *(const float4*)&hb[hq][((jq ^ (hq & 3)) << 2)];
        const float hvv[4] = {hv.x, hv.y, hv.z, hv.w};
        float wu[8];
        #pragma unroll
        for (int u = 0; u < 8; ++u) wu[u] = w2p[hq*H2 + u*16];
        #pragma unroll
        for (int u = 0; u < 8; ++u)
            #pragma unroll
            for (int jv = 0; jv < 4; ++jv)
                acc[jv][u] = fmaf(hvv[jv], wu[u], acc[jv][u]);
    }
    __syncthreads();            // hb reads complete before overwrite

    // ---- partials: part[qt*8+u][jq*4+jv][cc] (c contiguous) ----
    #pragma unroll
    for (int u = 0; u < 8; ++u)
        #pragma unroll
        for (int jv = 0; jv < 4; ++jv)
            part[(qt << 3) + u][(jq << 2) + jv][cc] = acc[jv][u];
    __syncthreads();

    // ---- epilogue: sum quarters, bias+relu, layer-3 dot over 128 c ----
    if (t < 128) {
        const int c  = t;
        const int ce = c & 15;
        const int ue = c >> 4;
        const float b2c = b2[c];
        const float w3c = W3[c];
        float y[16];
        #pragma unroll
        for (int jj = 0; jj < 16; ++jj) {
            const float s = part[0*8 + ue][jj][ce] + part[1*8 + ue][jj][ce]
                          + part[2*8 + ue][jj][ce] + part[3*8 + ue][jj][ce];
            y[jj] = fmaxf(s + b2c, 0.f) * w3c;
        }
        #pragma unroll
        for (int jj = 0; jj < 16; ++jj) {
            float s = y[jj];
            #pragma unroll
            for (int off = 32; off; off >>= 1) s += __shfl_down(s, off, 64);
            if ((t & 63) == 0) red[t >> 6][jj] = s;
        }
    }
    __syncthreads();
    if (t < 16) {
        const int j = j0 + t;
        const float s = red[0][t] + red[1][t] + b3[0];
        out[i*NN + j] = (i == j) ? 0.f : 1.f / (1.f + __expf(-s));
    }
}

// ---------------- Kernel C: conf [96,96,96] ----------------
// grid (96,12): 8 j per block, no LDS, no barriers. 192 threads = 4 j-groups
// x 48 k-pair lanes; each thread 2 j x 2 k. S rows stream from L1/L2
// (<=2 cache lines per wave-load); tcT coalesced over k. 1152 blocks =
// 4.5 blocks/CU = 13.5 waves/CU. Pure-VALU floor 8.6 us.
__global__ __launch_bounds__(192) void conf_kernel(
    const float* __restrict__ S, const float* __restrict__ tcT,
    const float* __restrict__ V2, const float* __restrict__ c2,
    float* __restrict__ out)
{
    const int i  = blockIdx.x;
    const int j0 = blockIdx.y * 8;
    const int t  = threadIdx.x;         // 0..191
    const int g  = t / 48;              // j-pair group 0..3
    const int l  = t - g*48;            // k-pair lane 0..47
    const int k0 = 2*l;

    const float* __restrict__ pS0 = S + (i*NN + j0 + g*2 + 0)*HH;
    const float* __restrict__ pS1 = pS0 + HH;

    float a00 = 0.f, a01 = 0.f, a10 = 0.f, a11 = 0.f;
    #pragma unroll 2
    for (int h0 = 0; h0 < HH; h0 += 4) {
        const float4 s0 = *(const float4*)&pS0[h0];
        const float4 s1 = *(const float4*)&pS1[h0];
        const float2 t0 = *(const float2*)&tcT[(h0+0)*NN + k0];
        const float2 t1 = *(const float2*)&tcT[(h0+1)*NN + k0];
        const float2 t2 = *(const float2*)&tcT[(h0+2)*NN + k0];
        const float2 t3 = *(const float2*)&tcT[(h0+3)*NN + k0];
        const float4 vv = *(const float4*)&V2[h0];          // uniform -> scalar
        const float sA[4]  = {s0.x, s0.y, s0.z, s0.w};
        const float sB[4]  = {s1.x, s1.y, s1.z, s1.w};
        const float tk0[4] = {t0.x, t1.x, t2.x, t3.x};
        const float tk1[4] = {t0.y, t1.y, t2.y, t3.y};
        const float vvv[4] = {vv.x, vv.y, vv.z, vv.w};
        #pragma unroll
        for (int u = 0; u < 4; ++u) {
            a00 = fmaf(fmaxf(sA[u] + tk0[u], 0.f), vvv[u], a00);
            a01 = fmaf(fmaxf(sA[u] + tk1[u], 0.f), vvv[u], a01);
            a10 = fmaf(fmaxf(sB[u] + tk0[u], 0.f), vvv[u], a10);
            a11 = fmaf(fmaxf(sB[u] + tk1[u], 0.f), vvv[u], a11);
        }
    }

    const float c2v = c2[0];
    const int jA = j0 + g*2, jB = jA + 1;
    float2 o0, o1;
    o0.x = 1.f / (1.f + __expf(-(a00 + c2v)));
    o0.y = 1.f / (1.f + __expf(-(a01 + c2v)));
    o1.x = 1.f / (1.f + __expf(-(a10 + c2v)));
    o1.y = 1.f / (1.f + __expf(-(a11 + c2v)));
    if (i == jA || i == k0   || jA == k0  ) o0.x = 0.f;
    if (i == jA || i == k0+1 || jA == k0+1) o0.y = 0.f;
    if (i == jB || i == k0   || jB == k0  ) o1.x = 0.f;
    if (i == jB || i == k0+1 || jB == k0+1) o1.y = 0.f;
    *(float2*)&out[(i*NN + jA)*NN + k0] = o0;
    *(float2*)&out[(i*NN + jB)*NN + k0] = o1;
}

extern "C" void kernel_launch(void* const* d_in, const int* in_sizes, int n_in,
                              void* d_out, int out_size, void* d_ws, size_t ws_size,
                              hipStream_t stream) {
    const float* X  = (const float*)d_in[0];
    // d_in[1] = edge_index (unused by reference)
    const float* W1 = (const float*)d_in[2];
    const float* b1 = (const float*)d_in[3];
    const float* W2 = (const float*)d_in[4];
    const float* b2 = (const float*)d_in[5];
    const float* W3 = (const float*)d_in[6];
    const float* b3 = (const float*)d_in[7];
    const float* V1 = (const float*)d_in[8];
    const float* c1 = (const float*)d_in[9];
    const float* V2 = (const float*)d_in[10];
    const float* c2 = (const float*)d_in[11];

    float* out = (float*)d_out;
    float* ws  = (float*)d_ws;
    float* pi  = ws;                 // 96*256
    float* pj  = pi + NN*HH;
    float* ta  = pj + NN*HH;
    float* tb  = ta + NN*HH;
    float* tcT = tb + NN*HH;         // 256*96
    float* S   = tcT + HH*NN;        // 9216*256 = 9.4 MB

    proj_kernel<<<NN, 256, 0, stream>>>(X, W1, b1, V1, c1, pi, pj, ta, tb, tcT);
    sadd_kernel<<<2304, 256, 0, stream>>>(ta, tb, S);
    causal_kernel<<<dim3(NN, 6), 256, 0, stream>>>(pi, pj, W2, b2, W3, b3, out);
    conf_kernel<<<dim3(NN, 12), 192, 0, stream>>>(S, tcT, V2, c2, out + NN*NN);
}

// Round 5
// 49.924 us; speedup vs baseline: 1.5670x; 1.5670x over previous
//
#include <hip/hip_runtime.h>
#include <hip/hip_bf16.h>

#define NN 96
#define DD 64
#define HH 256
#define H2 128

// ---------------- Kernel A: projections (round-2 proven form) ----------------
__global__ __launch_bounds__(256) void proj_kernel(
    const float* __restrict__ X, const float* __restrict__ W1, const float* __restrict__ b1,
    const float* __restrict__ V1, const float* __restrict__ c1,
    float* __restrict__ pi, float* __restrict__ pj,
    float* __restrict__ ta, float* __restrict__ tb, float* __restrict__ tcT)
{
    const int i = blockIdx.x;
    const int h = threadIdx.x;          // 0..255
    __shared__ float xs[DD];
    if (h < DD) xs[h] = X[i*DD + h];
    __syncthreads();
    float aPi = 0.f, aPj = 0.f, aTa = 0.f, aTb = 0.f, aTc = 0.f;
    #pragma unroll 8
    for (int d = 0; d < DD; ++d) {
        const float x = xs[d];
        aPi = fmaf(x, W1[d*HH + h],          aPi);
        aPj = fmaf(x, W1[(DD + d)*HH + h],   aPj);
        aTa = fmaf(x, V1[d*HH + h],          aTa);
        aTb = fmaf(x, V1[(DD + d)*HH + h],   aTb);
        aTc = fmaf(x, V1[(2*DD + d)*HH + h], aTc);
    }
    pi[i*HH + h] = aPi + b1[h];
    pj[i*HH + h] = aPj;
    ta[i*HH + h] = aTa + c1[h];
    tb[i*HH + h] = aTb;
    tcT[h*NN + i] = aTc;
}

// ---------------- Kernel B: causal [96,96] (round-2 proven form) ----------------
__global__ __launch_bounds__(256) void causal_kernel(
    const float* __restrict__ pi, const float* __restrict__ pj,
    const float* __restrict__ W2, const float* __restrict__ b2,
    const float* __restrict__ W3, const float* __restrict__ b3,
    float* __restrict__ out)
{
    const int i  = blockIdx.x;
    const int j0 = blockIdx.y * 12;
    const int t  = threadIdx.x;         // 0..255
    const int c2 = t & 63;
    const int qt = t >> 6;              // 0..3

    __shared__ float smem[4*64*2*12];   // 24 KB; staging then partials
    __shared__ float red[2][12];
    float (*hb)[12]          = (float(*)[12])smem;          // [256][12]
    float (*part)[64][2][12] = (float(*)[64][2][12])smem;   // [4][64][2][12]

    // ---- stage hbT[h][jj] = relu(pi[i][h] + pj[j][h]), h = t ----
    {
        const float p_i = pi[i*HH + t];
        #pragma unroll
        for (int jj = 0; jj < 12; ++jj)
            hb[t][jj] = fmaxf(p_i + pj[(j0 + jj)*HH + t], 0.f);
    }
    __syncthreads();

    float acc0[12], acc1[12];
    #pragma unroll
    for (int jj = 0; jj < 12; ++jj) { acc0[jj] = 0.f; acc1[jj] = 0.f; }

    const float* __restrict__ w2p = W2 + (qt*64)*H2 + c2;
    #pragma unroll 2
    for (int q = 0; q < 64; ++q) {
        const float wa = w2p[q*H2];
        const float wb = w2p[q*H2 + 64];
        const int hq = qt*64 + q;
        const float4 hA = *(const float4*)&hb[hq][0];
        const float4 hB = *(const float4*)&hb[hq][4];
        const float4 hC = *(const float4*)&hb[hq][8];
        const float hv[12] = {hA.x,hA.y,hA.z,hA.w, hB.x,hB.y,hB.z,hB.w, hC.x,hC.y,hC.z,hC.w};
        #pragma unroll
        for (int jj = 0; jj < 12; ++jj) {
            acc0[jj] = fmaf(hv[jj], wa, acc0[jj]);
            acc1[jj] = fmaf(hv[jj], wb, acc1[jj]);
        }
    }
    __syncthreads();          // all hb reads done before overwrite

    // ---- partials: part[qt][c2][cc][jj] ----
    #pragma unroll
    for (int b = 0; b < 3; ++b) {
        float4 p0, p1;
        p0.x = acc0[b*4+0]; p0.y = acc0[b*4+1]; p0.z = acc0[b*4+2]; p0.w = acc0[b*4+3];
        p1.x = acc1[b*4+0]; p1.y = acc1[b*4+1]; p1.z = acc1[b*4+2]; p1.w = acc1[b*4+3];
        *(float4*)&part[qt][c2][0][b*4] = p0;
        *(float4*)&part[qt][c2][1][b*4] = p1;
    }
    __syncthreads();

    // ---- reduce quarters, layer2 bias+relu, layer3 dot over 128 c ----
    if (t < 128) {
        const int c  = t;
        const int cl = t & 63;
        const int cc = t >> 6;
        const float b2c = b2[c];
        const float w3c = W3[c];
        float v[12];
        #pragma unroll
        for (int b = 0; b < 3; ++b) {
            float4 s; s.x = 0.f; s.y = 0.f; s.z = 0.f; s.w = 0.f;
            #pragma unroll
            for (int qq = 0; qq < 4; ++qq) {
                const float4 p = *(const float4*)&part[qq][cl][cc][b*4];
                s.x += p.x; s.y += p.y; s.z += p.z; s.w += p.w;
            }
            v[b*4+0] = fmaxf(s.x + b2c, 0.f) * w3c;
            v[b*4+1] = fmaxf(s.y + b2c, 0.f) * w3c;
            v[b*4+2] = fmaxf(s.z + b2c, 0.f) * w3c;
            v[b*4+3] = fmaxf(s.w + b2c, 0.f) * w3c;
        }
        #pragma unroll
        for (int jj = 0; jj < 12; ++jj) {
            float s = v[jj];
            #pragma unroll
            for (int off = 32; off; off >>= 1) s += __shfl_down(s, off, 64);
            if ((t & 63) == 0) red[t >> 6][jj] = s;
        }
    }
    __syncthreads();
    if (t < 12) {
        const int j = j0 + t;
        const float s = red[0][t] + red[1][t] + b3[0];
        out[i*NN + j] = (i == j) ? 0.f : 1.f / (1.f + __expf(-s));
    }
}

// ---------------- Kernel C: conf [96,96,96] ----------------
// grid (96,8) = 768 blocks = exactly 3/CU (9 waves/CU). 192 threads =
// 4 j-groups x (24 k-quads x 2 h-halves). Each thread: 3 j x 4 k over its
// 128-h half; lane pairs (t, t^1) combine halves via one shfl_xor.
// kpt=4 halves the DS-pipe cost vs round-2 (one b128 broadcast serves
// 64x4x4 element-ops); tc loads are aligned float4 (full k row per block).
// Row pad 260 keeps the dual-row reads bank-disjoint (hh aliasing is the
// free 2-way case).
#define CROW 260
__global__ __launch_bounds__(192) void conf_kernel(
    const float* __restrict__ ta, const float* __restrict__ tb,
    const float* __restrict__ tcT, const float* __restrict__ V2,
    const float* __restrict__ c2, float* __restrict__ out)
{
    const int i  = blockIdx.x;
    const int j0 = blockIdx.y * 12;
    const int t  = threadIdx.x;         // 0..191
    const int jg = t / 48;              // 0..3
    const int l  = t % 48;
    const int kp = l >> 1;              // 0..23
    const int hh = l & 1;               // h-half
    const int k0 = kp * 4;

    __shared__ float sbuf[12][CROW];    // padded rows, 12.2 KB

    // ---- stage s[jj][h] = ta[i][h] + tb[j][h] ----
    for (int idx = t; idx < 12*64; idx += 192) {
        const int jj = idx >> 6;
        const int h4 = (idx & 63) << 2;
        const float4 a = *(const float4*)&ta[i*HH + h4];
        const float4 b = *(const float4*)&tb[(j0 + jj)*HH + h4];
        float4 s; s.x = a.x + b.x; s.y = a.y + b.y; s.z = a.z + b.z; s.w = a.w + b.w;
        *(float4*)&sbuf[jj][h4] = s;
    }
    __syncthreads();

    float acc[3][4];
    #pragma unroll
    for (int m = 0; m < 3; ++m)
        #pragma unroll
        for (int x = 0; x < 4; ++x) acc[m][x] = 0.f;

    const int hbase = hh << 7;          // 0 or 128
    const float* __restrict__ sb0 = &sbuf[jg*3 + 0][hbase];
    const float* __restrict__ sb1 = &sbuf[jg*3 + 1][hbase];
    const float* __restrict__ sb2 = &sbuf[jg*3 + 2][hbase];
    const float* __restrict__ tp  = tcT + hbase*NN + k0;
    const float* __restrict__ vp  = V2 + hbase;

    #pragma unroll 2
    for (int hq = 0; hq < 128; hq += 4) {
        const float4 t0 = *(const float4*)&tp[(hq+0)*NN];
        const float4 t1 = *(const float4*)&tp[(hq+1)*NN];
        const float4 t2 = *(const float4*)&tp[(hq+2)*NN];
        const float4 t3 = *(const float4*)&tp[(hq+3)*NN];
        const float4 vv = *(const float4*)&vp[hq];
        const float4 sA = *(const float4*)&sb0[hq];
        const float4 sB = *(const float4*)&sb1[hq];
        const float4 sC = *(const float4*)&sb2[hq];
        const float sm[3][4] = {{sA.x,sA.y,sA.z,sA.w},
                                {sB.x,sB.y,sB.z,sB.w},
                                {sC.x,sC.y,sC.z,sC.w}};
        const float tk[4][4] = {{t0.x,t0.y,t0.z,t0.w},
                                {t1.x,t1.y,t1.z,t1.w},
                                {t2.x,t2.y,t2.z,t2.w},
                                {t3.x,t3.y,t3.z,t3.w}};
        const float vvv[4] = {vv.x, vv.y, vv.z, vv.w};
        #pragma unroll
        for (int u = 0; u < 4; ++u)
            #pragma unroll
            for (int m = 0; m < 3; ++m) {
                acc[m][0] = fmaf(fmaxf(sm[m][u] + tk[u][0], 0.f), vvv[u], acc[m][0]);
                acc[m][1] = fmaf(fmaxf(sm[m][u] + tk[u][1], 0.f), vvv[u], acc[m][1]);
                acc[m][2] = fmaf(fmaxf(sm[m][u] + tk[u][2], 0.f), vvv[u], acc[m][2]);
                acc[m][3] = fmaf(fmaxf(sm[m][u] + tk[u][3], 0.f), vvv[u], acc[m][3]);
            }
    }

    // ---- combine h-halves across lane pairs ----
    #pragma unroll
    for (int m = 0; m < 3; ++m)
        #pragma unroll
        for (int x = 0; x < 4; ++x)
            acc[m][x] += __shfl_xor(acc[m][x], 1, 64);

    if (hh == 0) {
        const float c2v = c2[0];
        #pragma unroll
        for (int m = 0; m < 3; ++m) {
            const int j = j0 + jg*3 + m;
            float4 o;
            o.x = 1.f / (1.f + __expf(-(acc[m][0] + c2v)));
            o.y = 1.f / (1.f + __expf(-(acc[m][1] + c2v)));
            o.z = 1.f / (1.f + __expf(-(acc[m][2] + c2v)));
            o.w = 1.f / (1.f + __expf(-(acc[m][3] + c2v)));
            if (i == j || i == k0   || j == k0  ) o.x = 0.f;
            if (i == j || i == k0+1 || j == k0+1) o.y = 0.f;
            if (i == j || i == k0+2 || j == k0+2) o.z = 0.f;
            if (i == j || i == k0+3 || j == k0+3) o.w = 0.f;
            *(float4*)&out[(i*NN + j)*NN + k0] = o;
        }
    }
}

extern "C" void kernel_launch(void* const* d_in, const int* in_sizes, int n_in,
                              void* d_out, int out_size, void* d_ws, size_t ws_size,
                              hipStream_t stream) {
    const float* X  = (const float*)d_in[0];
    // d_in[1] = edge_index (unused by reference)
    const float* W1 = (const float*)d_in[2];
    const float* b1 = (const float*)d_in[3];
    const float* W2 = (const float*)d_in[4];
    const float* b2 = (const float*)d_in[5];
    const float* W3 = (const float*)d_in[6];
    const float* b3 = (const float*)d_in[7];
    const float* V1 = (const float*)d_in[8];
    const float* c1 = (const float*)d_in[9];
    const float* V2 = (const float*)d_in[10];
    const float* c2 = (const float*)d_in[11];

    float* out = (float*)d_out;
    float* ws  = (float*)d_ws;
    float* pi  = ws;                 // 96*256
    float* pj  = pi + NN*HH;
    float* ta  = pj + NN*HH;
    float* tb  = ta + NN*HH;
    float* tcT = tb + NN*HH;         // 256*96

    proj_kernel<<<NN, 256, 0, stream>>>(X, W1, b1, V1, c1, pi, pj, ta, tb, tcT);
    causal_kernel<<<dim3(NN, 8), 256, 0, stream>>>(pi, pj, W2, b2, W3, b3, out);
    conf_kernel<<<dim3(NN, 8), 192, 0, stream>>>(ta, tb, tcT, V2, c2, out + NN*NN);
}